// Round 3
// baseline (357.913 us; speedup 1.0000x reference)
//
#include <hip/hip_runtime.h>
#include <hip/hip_bf16.h>
#include <math.h>

// Memory-bound streaming: 256 MB read + 32 MB write per launch (~48 us @ 6.3 TB/s).
// Round-3 experiment: perfectly lane-contiguous global loads (stride 16 B/lane,
// same pattern as the 6.7 TB/s fill kernel) staged through LDS, replacing the
// previous lane-stride-32B float4 pair loads. Tests whether the strided pattern
// was costing DRAM/L2 efficiency.

__device__ __forceinline__ float fast_rcp(float x) {
    return __builtin_amdgcn_rcpf(x);
}

// tanh(x) = sign(x) * (1 - 2e/(1+e)), e = exp(-2|x|). Branch-free, saturates to +/-1.
__device__ __forceinline__ float fast_tanh(float x) {
    float a = fabsf(x);
    float e = __expf(-2.0f * a);
    float r = fast_rcp(1.0f + e);
    float t = __builtin_fmaf(-(e + e), r, 1.0f);
    return copysignf(t, x);
}

__device__ __forceinline__ float row_expr(float4 a, float4 b) {
    float s  = __sinf(a.z);
    float e3 = __expf(-fabsf(a.w));
    float t1 = __builtin_fmaf(a.x, a.y, s) * e3;          // (x0*x1+sin(x2))*exp(-|x3|)
    float den = __builtin_fmaf(b.y, b.y, __expf(b.z));    // x5*x5 + exp(x6)
    float t2 = b.x * fast_rcp(den);                       // x4 / den
    return fast_tanh(t1 + t2 - b.w);
}

#define BLOCK 256
#define ROWS_PER_BLOCK 512   // 512 rows * 32 B = 16 KB LDS; 2 rows/thread

__global__ __launch_bounds__(BLOCK) void Expression_82643760709953_kernel(
    const float4* __restrict__ in4, float* __restrict__ out, int n_rows) {
    __shared__ float4 tile[ROWS_PER_BLOCK * 2];  // 16 KB
    const int t = threadIdx.x;
    const long long base_row = (long long)blockIdx.x * ROWS_PER_BLOCK;
    const float4* gsrc = in4 + base_row * 2;

    // Stage 1: 4 perfectly-coalesced float4 loads (lane-stride 16 B) -> LDS (contiguous).
    #pragma unroll
    for (int k = 0; k < 4; ++k) {
        int idx = k * BLOCK + t;
        tile[idx] = gsrc[idx];
    }
    __syncthreads();

    // Stage 2: thread t computes rows t and t+256 of this block's 512-row tile.
    {
        float4 a = tile[2 * t];
        float4 b = tile[2 * t + 1];
        long long r = base_row + t;
        if (r < n_rows) out[r] = row_expr(a, b);
    }
    {
        int lt = t + BLOCK;
        float4 a = tile[2 * lt];
        float4 b = tile[2 * lt + 1];
        long long r = base_row + lt;
        if (r < n_rows) out[r] = row_expr(a, b);
    }
}

extern "C" void kernel_launch(void* const* d_in, const int* in_sizes, int n_in,
                              void* d_out, int out_size, void* d_ws, size_t ws_size,
                              hipStream_t stream) {
    const float4* in4 = (const float4*)d_in[0];
    float* out = (float*)d_out;
    int n_rows = out_size;  // 8388608
    int grid = (n_rows + ROWS_PER_BLOCK - 1) / ROWS_PER_BLOCK;  // 16384 blocks
    Expression_82643760709953_kernel<<<grid, BLOCK, 0, stream>>>(in4, out, n_rows);
}